// Round 5
// baseline (8319.553 us; speedup 1.0000x reference)
//
#include <hip/hip_runtime.h>
#include <cstdint>

// CharRNN fused kernel, round 5 — MI355X (gfx950).
//
// Topology: 8 clusters x 16 members = 128 wgs. Cluster c owns batch rows
// [16c,16c+16). Member m owns hidden outputs [32m,32m+32) (W_hh bf16 hi+lo
// register-resident) and vocab rows [8m,8m+8) of W_fc (k split, waves 2/3).
//
// Numerics: IDENTICAL to r2-r4 (passed, absmax 7.8e-3): W_hh hi+lo bf16
// 3-term MFMA; h as 21-bit fixed point + 11-bit gen tag per u32; fp32 acc.
//
// Round-5 exchange (r4's single atomicAdd counter serialized 32 RMWs/gen on
// a line being hammered by 64 polling waves, and the gate fired before the
// data was visible -> 1-3 wasted full re-sweeps; 7700 cy/step):
//  - 32 per-writer-wave FLAG words (one 128B line per cluster, memset 0).
//    Writers publish data (relaxed agent atomics) then RELEASE-store flag=t+1
//    (release => vmcnt(0) drain => flag visible implies data visible).
//  - Readers: coalesced one-line poll with monotone predicate (flag >= t,
//    full 32-bit - no wrap/overwrite deadlock), one ACQUIRE load to pair,
//    then plain dwordx4 sweep (8 loads/thread). Embedded tags verified;
//    atomic-load retry loop is the backstop (also beats any stale-cache
//    livelock since atomics bypass L1/L2).
//  - conversion: u16x4 + ds_write_b64 at 520-short padded chunk stride:
//    kills the 8-way ds_write_b16 conflicts (2.05e8 counted in r4).

typedef short bf16x8 __attribute__((ext_vector_type(8)));
typedef float f32x4 __attribute__((ext_vector_type(4)));
typedef unsigned short u16x4 __attribute__((ext_vector_type(4)));

#define VOCAB 128
#define EMB   16
#define HID   512
#define TT    1024
#define NCL   8      // clusters
#define BB    16     // batch rows per cluster
#define JC    32     // hidden outputs per member
#define NWG   128
#define BUFW  (NCL * BB * HID)   // 65536 words per generation buffer
#define FLGOFF (2 * BUFW)        // u32 index of flag region (NCL x 32 u32)
#define PJC   33                 // padded ep stride
#define CS    520                // padded chunk stride (shorts) for a_hi/a_lo

__device__ __forceinline__ unsigned short f2bf(float f) {
  uint32_t u = __builtin_bit_cast(uint32_t, f);
  u += 0x7FFFu + ((u >> 16) & 1u);
  return (unsigned short)(u >> 16);
}
__device__ __forceinline__ float bf2f(unsigned short s) {
  uint32_t u = (uint32_t)s << 16;
  return __builtin_bit_cast(float, u);
}
__device__ __forceinline__ float ftanh(float z) {
  z = fminf(15.f, fmaxf(-15.f, z));
  float e = __expf(2.f * z);
  return (e - 1.f) * __builtin_amdgcn_rcpf(e + 1.f);
}
__device__ __forceinline__ uint32_t aload(const uint32_t* p) {
  return __hip_atomic_load(p, __ATOMIC_RELAXED, __HIP_MEMORY_SCOPE_AGENT);
}
__device__ __forceinline__ void astore(uint32_t* p, uint32_t v) {
  __hip_atomic_store(p, v, __ATOMIC_RELAXED, __HIP_MEMORY_SCOPE_AGENT);
}

// Sweep one batch row (512 words) cooperatively (32 lane-slots via lw),
// verify tags, convert 21-bit fixed -> bf16 hi/lo frag-order LDS.
__device__ __forceinline__ void sweep_row(const uint32_t* prow, int lw, int row,
                                          uint32_t tag,
                                          unsigned short* a_hi,
                                          unsigned short* a_lo) {
  uint32_t w[16];
  const uint4* pv = (const uint4*)(prow + lw * 4);
  uint4 q0 = pv[0], q1 = pv[32], q2 = pv[64], q3 = pv[96];   // +i*128 words
  w[0]=q0.x; w[1]=q0.y; w[2]=q0.z; w[3]=q0.w;
  w[4]=q1.x; w[5]=q1.y; w[6]=q1.z; w[7]=q1.w;
  w[8]=q2.x; w[9]=q2.y; w[10]=q2.z; w[11]=q2.w;
  w[12]=q3.x; w[13]=q3.y; w[14]=q3.z; w[15]=q3.w;
  uint32_t bad = 0;
  #pragma unroll
  for (int i = 0; i < 16; ++i) bad |= (w[i] ^ tag);
  while (bad & 0x7FFu) {        // backstop: atomic reloads (bypass caches)
    bad = 0;
    #pragma unroll
    for (int i = 0; i < 16; ++i) {
      w[i] = aload(prow + lw * 4 + (i >> 2) * 128 + (i & 3));
      bad |= (w[i] ^ tag);
    }
  }
  const float rcp20 = 1.f / 1048576.f;
  const int qk = (lw >> 1) & 3, jh = (lw & 1) * 4, ksb = lw >> 3;
  #pragma unroll
  for (int i = 0; i < 4; ++i) {
    const int sa = (i * 4 + ksb) * CS + (qk * 16 + row) * 8 + jh;
    u16x4 hv, lv;
    #pragma unroll
    for (int q = 0; q < 4; ++q) {
      float h = (float)(((int)w[i * 4 + q]) >> 11) * rcp20;
      uint32_t uh = __builtin_bit_cast(uint32_t, h) & 0xFFFF0000u;
      float l = h - __builtin_bit_cast(float, uh);
      hv[q] = (unsigned short)(uh >> 16);
      lv[q] = (unsigned short)(__builtin_bit_cast(uint32_t, l) >> 16);
    }
    *(u16x4*)&a_hi[sa] = hv;
    *(u16x4*)&a_lo[sa] = lv;
  }
}

__global__ __launch_bounds__(256, 1) void charrnn_kernel(
    const int* __restrict__ xin,
    const float* __restrict__ emb,
    const float* __restrict__ wih,
    const float* __restrict__ whh,
    const float* __restrict__ bih,
    const float* __restrict__ bhh,
    const float* __restrict__ wfc,
    const float* __restrict__ bfc,
    float* __restrict__ out,
    uint32_t* __restrict__ hx)
{
  // frag-order h state: a[ks*CS + (qk*16 + row)*8 + j]
  __shared__ __align__(16) unsigned short a_hi[16 * CS];    // 16.6 KB
  __shared__ __align__(16) unsigned short a_lo[16 * CS];    // 16.6 KB
  __shared__ float ep[VOCAB * PJC];                         // 16.9 KB
  __shared__ unsigned char xtok[BB * TT];                   // 16 KB
  __shared__ __align__(16) float red[2][256];               // 2 KB logits partials

  const int tid  = threadIdx.x;
  const int wave = tid >> 6;
  const int lane = tid & 63;
  const int col  = lane & 15;
  const int quad = lane >> 4;
  const int cl   = blockIdx.x & 7;   // members of a cluster share blockIdx mod 8
  const int m    = blockIdx.x >> 3;  // -> same XCD under round-robin (perf hint)

  // ---- weight fragments -> registers (global gather, one-time) ----
  bf16x8 wfh[16], wfl[16], wfcf[8];
  if (wave < 2) {
    const int nrow = m * JC + wave * 16 + col;
    const float* wr = whh + (size_t)nrow * HID + quad * 8;
    #pragma unroll
    for (int ks = 0; ks < 16; ++ks) {
      bf16x8 hi, lo;
      #pragma unroll
      for (int j = 0; j < 8; ++j) {
        float w = wr[ks * 32 + j];
        unsigned short h = f2bf(w);
        hi[j] = (short)h;
        lo[j] = (short)f2bf(w - bf2f(h));
      }
      wfh[ks] = hi; wfl[ks] = lo;
    }
  } else {
    const int vrow = m * 8 + (col & 7);
    const float* wr = wfc + (size_t)vrow * HID + (wave - 2) * 256 + quad * 8;
    #pragma unroll
    for (int ks = 0; ks < 8; ++ks) {
      bf16x8 f;
      #pragma unroll
      for (int j = 0; j < 8; ++j) f[j] = (short)f2bf(wr[ks * 32 + j]);
      wfcf[ks] = f;
    }
  }
  const float bfcr = bfc[m * 8 + (col & 7)];

  // ---- LDS init: h0 = 0, ep table, tokens ----
  for (int i = tid; i < 16 * CS; i += 256) { a_hi[i] = 0; a_lo[i] = 0; }
  for (int i = tid; i < VOCAB * JC; i += 256) {
    int v = i >> 5, jl = i & 31;
    int jg = m * JC + jl;
    float s = bih[jg] + bhh[jg];
    #pragma unroll
    for (int e = 0; e < EMB; ++e) s += emb[v * EMB + e] * wih[jg * EMB + e];
    ep[v * PJC + jl] = s;
  }
  for (int i = tid; i < BB * TT; i += 256) {
    int b = i >> 10, t = i & 1023;
    xtok[i] = (unsigned char)xin[(cl * BB + b) * TT + t];
  }
  __syncthreads();

  // ---- main time loop ----
  const int lw = tid & 31;
  const int r0 = tid >> 5;                 // rows r0 and r0+8
  uint32_t* const flags = hx + FLGOFF + cl * 32;
  f32x4 prev_lacc = {0.f, 0.f, 0.f, 0.f};

  #pragma unroll 1
  for (int t = 0; t <= TT + 1; ++t) {
    const int par = t & 1;
    const uint32_t tag = (uint32_t)t & 0x7FFu;
    const uint32_t* const p0 = hx + par * BUFW + (cl * BB + r0) * HID;
    const uint32_t* const p1 = p0 + 8 * HID;

    // -- phase A: logits partials (computed in prior C) to LDS --
    if (wave >= 2 && t >= 2) {
      *(f32x4*)&red[wave - 2][lane * 4] = prev_lacc;
    }

    // -- phase B: flag gate (monotone), acquire, sweep + convert --
    if (t >= 1 && t <= TT) {
      const int fl = lane & 31;
      while ((int32_t)(aload(flags + fl) - (uint32_t)t) < 0) {}
      (void)__hip_atomic_load(flags + fl, __ATOMIC_ACQUIRE, __HIP_MEMORY_SCOPE_AGENT);
      sweep_row(p0, lw, r0,     tag, a_hi, a_lo);
      sweep_row(p1, lw, r0 + 8, tag, a_hi, a_lo);
    }
    __syncthreads();  // B1: lds_a(gen t) ready; red stored

    // -- phase C --
    if (wave < 2) {
      // recurrence: gen t -> gen t+1 (3-term hi/lo MFMA), publish + flag
      if (t < TT) {
        f32x4 acc0 = {0.f,0.f,0.f,0.f}, acc1 = {0.f,0.f,0.f,0.f}, acc2 = {0.f,0.f,0.f,0.f};
        #pragma unroll
        for (int ks = 0; ks < 16; ++ks) {
          bf16x8 ah = *(const bf16x8*)&a_hi[ks * CS + lane * 8];
          bf16x8 al = *(const bf16x8*)&a_lo[ks * CS + lane * 8];
          acc0 = __builtin_amdgcn_mfma_f32_16x16x32_bf16(ah, wfh[ks], acc0, 0, 0, 0);
          acc1 = __builtin_amdgcn_mfma_f32_16x16x32_bf16(al, wfh[ks], acc1, 0, 0, 0);
          acc2 = __builtin_amdgcn_mfma_f32_16x16x32_bf16(ah, wfl[ks], acc2, 0, 0, 0);
        }
        const int jl = wave * 16 + col;
        const uint32_t ntag = (uint32_t)(t + 1) & 0x7FFu;
        uint32_t* wb = hx + ((t + 1) & 1) * BUFW + (cl * BB) * HID + m * JC + jl;
        #pragma unroll
        for (int i = 0; i < 4; ++i) {
          const int b = quad * 4 + i;
          float z = acc0[i] + acc1[i] + acc2[i]
                  + ep[(int)xtok[b * TT + t] * PJC + jl];
          float h = ftanh(z);
          int q = __float2int_rn(h * 1048576.f);
          q = max(min(q, 1048575), -1048576);
          astore(wb + b * HID, ((uint32_t)q << 11) | ntag);
        }
        if (lane == 0)
          __hip_atomic_store(flags + (m * 2 + wave), (uint32_t)(t + 1),
                             __ATOMIC_RELEASE, __HIP_MEMORY_SCOPE_AGENT);
      }
    } else {
      // reduce + store logits for time t-2 (wave 2; partials in red from A)
      if (wave == 2 && t >= 2 && col < 8) {
        #pragma unroll
        for (int i = 0; i < 4; ++i) {
          const int b = quad * 4 + i;
          float s = red[0][lane * 4 + i] + red[1][lane * 4 + i] + bfcr;
          out[((size_t)(cl * BB + b) * TT + (t - 2)) * VOCAB + m * 8 + col] = s;
        }
      }
      // logits MFMA for time t-1 (k-half per wave, hi+lo terms)
      if (t >= 1 && t <= TT) {
        f32x4 lacc = {0.f, 0.f, 0.f, 0.f};
        const int kb = (wave - 2) * 8;
        #pragma unroll
        for (int ks = 0; ks < 8; ++ks) {
          bf16x8 ah = *(const bf16x8*)&a_hi[(kb + ks) * CS + lane * 8];
          bf16x8 al = *(const bf16x8*)&a_lo[(kb + ks) * CS + lane * 8];
          lacc = __builtin_amdgcn_mfma_f32_16x16x32_bf16(ah, wfcf[ks], lacc, 0, 0, 0);
          lacc = __builtin_amdgcn_mfma_f32_16x16x32_bf16(al, wfcf[ks], lacc, 0, 0, 0);
        }
        prev_lacc = lacc;
      }
    }
    __syncthreads();  // B2: lds_a consumed; red consumed
  }
}

extern "C" void kernel_launch(void* const* d_in, const int* in_sizes, int n_in,
                              void* d_out, int out_size, void* d_ws, size_t ws_size,
                              hipStream_t stream) {
  (void)in_sizes; (void)n_in; (void)out_size;
  if (ws_size < (size_t)FLGOFF * sizeof(uint32_t) + 4096) return;  // 512 KB + flags

  const int*   x    = (const int*)d_in[0];
  const float* embp = (const float*)d_in[1];
  const float* W_ih = (const float*)d_in[2];
  const float* W_hh = (const float*)d_in[3];
  const float* b_ih = (const float*)d_in[4];
  const float* b_hh = (const float*)d_in[5];
  const float* W_fc = (const float*)d_in[6];
  const float* b_fc = (const float*)d_in[7];

  // zero the per-cluster flag lines (NCL x 32 u32); data region keeps poison
  hipMemsetAsync((uint32_t*)d_ws + FLGOFF, 0, NCL * 32 * sizeof(uint32_t), stream);

  charrnn_kernel<<<NWG, 256, 0, stream>>>(x, embp, W_ih, W_hh, b_ih, b_hh, W_fc, b_fc,
                                          (float*)d_out, (uint32_t*)d_ws);
}